// Round 13
// baseline (315.788 us; speedup 1.0000x reference)
//
#include <hip/hip_runtime.h>
#include <math.h>

// GATv2 3-layer forward, MI355X.
// R25: LDS-free gemm1. R24 landed 308.5 (delta algebra validated). Top
// dispatch gemm1_count ~53us, latency-bound (VALU 4%, Mfma 1%, HBM 16%),
// occupancy 35% — capped by 27.6KB LDS (<=5 blocks/CU), which the 3165
// count blocks also pay for (static LDS is per-kernel). Fix: gemm_body
// loads A-frags per-lane directly from x (2x32B contiguous fp32 runs,
// L2/L3-cached) and B-frags per-lane from wt (16KB L2-hot — the exact
// pattern validated in the R21 agg epilogue). No LDS, no barriers; count
// blocks freed from the phantom allocation. Single-variable change vs R24.
// Everything else = R24: slice-sorted CSR (SLSHIFT=13), dual-edge agg,
// no-max softmax, GEMM-in-epilogue (L2-direct B-frags, o_sh coalesced
// stores), single-edge rank-capturing count, R19b preamble structure.
// N=100000, E=800000 (+N self loops), Fin=64, H=4, C=16/16/32.

#define HEADS 4
#define NSLOPE 0.2f
#define SLSHIFT 13  // source-slice = 8192 nodes (2MB of layer-3 xl rows)

typedef __attribute__((ext_vector_type(8))) _Float16 half8;
typedef __attribute__((ext_vector_type(2))) _Float16 h2;
typedef __attribute__((ext_vector_type(4))) float f32x4;

union H8 {
  half8 v;
  h2 h[4];
};

// ---------------------------------------------------------------------------
// K1: build fp16 W^T for all 3 layers (wt[c*64+k] = W[k][c], combined
// [Wl | Wr] cols) + zero cnt2/hist/cursor2.
__global__ __launch_bounds__(256) void wt_build_zero_kernel(
    const float* __restrict__ W1l, const float* __restrict__ W1r,
    const float* __restrict__ W2l, const float* __restrict__ W2r,
    const float* __restrict__ W3l, const float* __restrict__ W3r,
    _Float16* __restrict__ wt1, _Float16* __restrict__ wt2,
    _Float16* __restrict__ wt3, int* __restrict__ cnt2, int* __restrict__ hist,
    int* __restrict__ cursor2, int NZ) {
  const int tid = blockIdx.x * 256 + threadIdx.x;
  for (int i = tid; i < NZ; i += gridDim.x * 256) cnt2[i] = 0;
  if (tid < 64) {
    hist[tid] = 0;
    cursor2[tid] = 0;
  }
  int i = tid;
  const float *Wl, *Wr;
  _Float16* wt;
  int COLS;
  if (i < 8192) {
    Wl = W1l; Wr = W1r; wt = wt1; COLS = 64;
  } else if (i < 16384) {
    i -= 8192; Wl = W2l; Wr = W2r; wt = wt2; COLS = 64;
  } else if (i < 32768) {
    i -= 16384; Wl = W3l; Wr = W3r; wt = wt3; COLS = 128;
  } else {
    return;
  }
  const int c = i >> 6, k = i & 63;
  const float v = (c < COLS) ? Wl[k * COLS + c] : Wr[k * COLS + (c - COLS)];
  wt[i] = (_Float16)v;
}

// ---------------------------------------------------------------------------
// MFMA GEMM body (layer 1: 128 combined cols, fp32 input): [xl|xr] =
// in @ [Wl|Wr], K=64, mfma_f32_16x16x32_f16, 64 rows x 128 cols, 4 waves.
// LDS-FREE: A-frag per-lane from x (row m0+lm, k=lq*8..+8 and 32+lq*8..+8,
// two 32B fp32 runs, fp32->fp16 in reg); B-frag per-lane from wt (L2-hot).
// A-frag: A[m=lane&15][k=quad*8+j]; B-frag: B[k=quad*8+j][n=lane&15];
// C/D: col=lane&15, row=quad*4+reg (m89-verified mapping).
// Direct fragment writes (R24 measured-best form).
__device__ __forceinline__ void gemm_body(const float* __restrict__ inf,
                                          const _Float16* __restrict__ wt,
                                          _Float16* __restrict__ xl,
                                          _Float16* __restrict__ xr, int N,
                                          int bx) {
  const int row0 = bx * 64;
  const int t = threadIdx.x;
  const int lane = t & 63, w = t >> 6;
  const int lm = lane & 15, lq = lane >> 4;
  const int m0 = w * 16;

  // A-fragments: lane owns row m0+lm, k-ranges [lq*8, +8) and [32+lq*8, +8).
  const int arow = row0 + m0 + lm;
  half8 a0, a1;
  if (arow < N) {
    const float4* xp = (const float4*)(inf + (size_t)arow * 64 + lq * 8);
    const float4 q0 = xp[0], q1 = xp[1];
    const float4* xp2 =
        (const float4*)(inf + (size_t)arow * 64 + 32 + lq * 8);
    const float4 r0 = xp2[0], r1 = xp2[1];
    a0[0] = (_Float16)q0.x; a0[1] = (_Float16)q0.y;
    a0[2] = (_Float16)q0.z; a0[3] = (_Float16)q0.w;
    a0[4] = (_Float16)q1.x; a0[5] = (_Float16)q1.y;
    a0[6] = (_Float16)q1.z; a0[7] = (_Float16)q1.w;
    a1[0] = (_Float16)r0.x; a1[1] = (_Float16)r0.y;
    a1[2] = (_Float16)r0.z; a1[3] = (_Float16)r0.w;
    a1[4] = (_Float16)r1.x; a1[5] = (_Float16)r1.y;
    a1[6] = (_Float16)r1.z; a1[7] = (_Float16)r1.w;
  } else {
#pragma unroll
    for (int j = 0; j < 8; j++) {
      a0[j] = (_Float16)0.f;
      a1[j] = (_Float16)0.f;
    }
  }

  f32x4 acc[8];
#pragma unroll
  for (int nt = 0; nt < 8; nt++) {
    const _Float16* wrow = wt + ((size_t)(nt * 16 + lm) << 6);
    const half8 b0 = *(const half8*)(wrow + lq * 8);
    const half8 b1 = *(const half8*)(wrow + 32 + lq * 8);
    f32x4 c = {0.f, 0.f, 0.f, 0.f};
    c = __builtin_amdgcn_mfma_f32_16x16x32_f16(a0, b0, c, 0, 0, 0);
    c = __builtin_amdgcn_mfma_f32_16x16x32_f16(a1, b1, c, 0, 0, 0);
    acc[nt] = c;
  }

  const int rbase = row0 + m0 + lq * 4;
#pragma unroll
  for (int nt = 0; nt < 8; nt++) {
    const int cn = nt * 16 + lm;  // combined col (branch wave-uniform)
    if (cn < 64) {
#pragma unroll
      for (int r = 0; r < 4; r++)
        if (rbase + r < N)
          xl[(size_t)(rbase + r) * 64 + cn] = (_Float16)acc[nt][r];
    } else {
      const int cx = cn - 64;
#pragma unroll
      for (int r = 0; r < 4; r++)
        if (rbase + r < N)
          xr[(size_t)(rbase + r) * 64 + cx] = (_Float16)acc[nt][r];
    }
  }
}

// ---------------------------------------------------------------------------
// count body (R21 form): per-(dst, src-slice) count, capturing per-edge rank
// WITHIN the slice bucket. cnt2 layout [NS][N] (transposed).
__device__ __forceinline__ void count_body(const int* __restrict__ ei, int E,
                                           int ET, int N,
                                           int* __restrict__ cnt2,
                                           int* __restrict__ rank, int e) {
  if (e >= ET) return;
  const int d = (e < E) ? ei[E + e] : (e - E);
  const int s = (e < E) ? ei[e] : d;
  rank[e] = atomicAdd(cnt2 + (size_t)(s >> SLSHIFT) * N + d, 1);
}

// K2: fused gemm1 (blocks [0,GB)) + count (blocks [GB, GB+edgeBlocks)).
__global__ __launch_bounds__(256) void gemm1_count_kernel(
    const float* __restrict__ x, const _Float16* __restrict__ wt1,
    _Float16* __restrict__ xl, _Float16* __restrict__ xr,
    const int* __restrict__ ei, int E, int ET, int N, int* __restrict__ cnt2,
    int* __restrict__ rank, int GB) {
  if ((int)blockIdx.x < GB) {
    gemm_body(x, wt1, xl, xr, N, blockIdx.x);
  } else {
    count_body(ei, E, ET, N, cnt2, rank,
               ((int)blockIdx.x - GB) * 256 + (int)threadIdx.x);
  }
}

// ---------------------------------------------------------------------------
// K3: fused slice-offset scan + degree output + block prefix scan + degree
// histogram. Per block: 1024 nodes (int4/thread). Writes per-block exclusive
// prefix into row_ofs (block base added in finalize2).
__global__ __launch_bounds__(256) void slicescan_kernel(
    int* __restrict__ cnt2, int* __restrict__ deg, int* __restrict__ pre,
    int* __restrict__ bsums, int* __restrict__ hist, int N, int NS) {
  __shared__ int lh[64];
  __shared__ int wsum[4];
  const int t = threadIdx.x;
  if (t < 64) lh[t] = 0;
  __syncthreads();
  const int i0 = blockIdx.x * 1024 + t * 4;
  int4 v;  // degrees of the 4 owned nodes
  if (i0 + 3 < N) {
    int rx = 0, ry = 0, rz = 0, rw = 0;
    for (int k = 0; k < NS; k++) {
      int* pp = cnt2 + (size_t)k * N + i0;
      const int4 c = *(const int4*)pp;
      int4 o; o.x = rx; o.y = ry; o.z = rz; o.w = rw;
      *(int4*)pp = o;
      rx += c.x; ry += c.y; rz += c.z; rw += c.w;
    }
    v.x = rx; v.y = ry; v.z = rz; v.w = rw;
    *(int4*)(deg + i0) = v;
    atomicAdd(&lh[min(v.x, 63)], 1);
    atomicAdd(&lh[min(v.y, 63)], 1);
    atomicAdd(&lh[min(v.z, 63)], 1);
    atomicAdd(&lh[min(v.w, 63)], 1);
  } else {
    int rr[4] = {0, 0, 0, 0};
    for (int e2 = 0; e2 < 4; e2++) {
      const int idx = i0 + e2;
      if (idx < N) {
        int run = 0;
        for (int k = 0; k < NS; k++) {
          int* pp = cnt2 + (size_t)k * N + idx;
          const int c = *pp;
          *pp = run;
          run += c;
        }
        deg[idx] = run;
        rr[e2] = run;
        atomicAdd(&lh[min(run, 63)], 1);
      }
    }
    v.x = rr[0]; v.y = rr[1]; v.z = rr[2]; v.w = rr[3];
  }
  const int s = v.x + v.y + v.z + v.w;
  const int lane = t & 63, wave = t >> 6;
  int x = s;
#pragma unroll
  for (int off = 1; off < 64; off <<= 1) {
    const int y = __shfl_up(x, off);
    if (lane >= off) x += y;
  }
  if (lane == 63) wsum[wave] = x;
  __syncthreads();
  int wbase = 0;
#pragma unroll
  for (int w = 0; w < 3; w++)
    if (w < wave) wbase += wsum[w];
  const int ex = wbase + (x - s);
  if (i0 + 3 < N) {
    int4 o;
    o.x = ex;
    o.y = ex + v.x;
    o.z = o.y + v.y;
    o.w = o.z + v.z;
    *(int4*)(pre + i0) = o;
  } else {
    int run = ex;
    if (i0 + 0 < N) pre[i0 + 0] = run;
    run += v.x;
    if (i0 + 1 < N) pre[i0 + 1] = run;
    run += v.y;
    if (i0 + 2 < N) pre[i0 + 2] = run;
    run += v.z;
    if (i0 + 3 < N) pre[i0 + 3] = run;
  }
  if (t == 255) bsums[blockIdx.x] = wbase + x;  // block total
  if (t < 64 && lh[t] > 0) atomicAdd(hist + t, lh[t]);
}

// ---------------------------------------------------------------------------
// K4: finalize with scan2 folded in (cursor2 = cross-block bin cursor).
// row_ofs[i] += block base (slicescan wrote the per-block prefix).
__global__ __launch_bounds__(256) void finalize2_kernel(
    int* __restrict__ row_ofs, const int* __restrict__ bsums,
    const int* __restrict__ deg, const int* __restrict__ hist,
    int* __restrict__ cursor2, int* __restrict__ order, int N, int ET, int B) {
  __shared__ int sbs[128];
  __shared__ int ws0s;
  __shared__ int lh[64];
  __shared__ int base[64];
  const int t = threadIdx.x;
  int xv = 0, vv = 0;
  if (t < 128) {
    const int lane = t & 63;
    vv = (t < B) ? bsums[t] : 0;
    xv = vv;
#pragma unroll
    for (int off = 1; off < 64; off <<= 1) {
      const int y = __shfl_up(xv, off);
      if (lane >= off) xv += y;
    }
    if (t == 63) ws0s = xv;
  }
  if (t < 64) lh[t] = 0;
  __syncthreads();
  if (t < 128) sbs[t] = ((t >> 6) ? ws0s : 0) + xv - vv;  // exclusive
  __syncthreads();

  const int i = blockIdx.x * 256 + t;
  const int q = blockIdx.x >> 2;  // 256-node block -> constant 1024-chunk id
  if (i == 0) row_ofs[N] = ET;
  int b = 0, r = 0;
  if (i < N) {
    row_ofs[i] += sbs[q];
    b = min(deg[i], 63);
    r = atomicAdd(&lh[b], 1);
  }
  __syncthreads();
  if (t < 64) {
    const int bin = 63 - t;  // lane order = descending degree bins
    const int rv = hist[bin];
    int xx = rv;
#pragma unroll
    for (int off = 1; off < 64; off <<= 1) {
      const int y = __shfl_up(xx, off);
      if (t >= off) xx += y;
    }
    int bb = xx - rv;  // exclusive sum of higher-degree bins
    const int cnt = lh[bin];
    if (cnt > 0) bb += atomicAdd(cursor2 + bin, cnt);
    base[bin] = bb;
  }
  __syncthreads();
  if (i < N) order[base[b] + r] = i;
}

// XCD-sliced CSR fill (slice-sorted positions via cnt2 base + rank).
__global__ __launch_bounds__(256) void fill_kernel(
    const int* __restrict__ ei, const int* __restrict__ rank,
    const int* __restrict__ row_ofs, const int* __restrict__ cnt2, int E,
    int ET, int N, int nSlice, int* __restrict__ csr_src) {
  const int xcd = blockIdx.x & 7;
  const int bId = blockIdx.x >> 3;
  const int nB = gridDim.x >> 3;
  const int dlo = xcd * nSlice, dhi = dlo + nSlice;
  for (int e = bId * 256 + threadIdx.x; e < ET; e += nB * 256) {
    const int d = (e < E) ? ei[E + e] : (e - E);
    if (d < dlo || d >= dhi) continue;
    const int s = (e < E) ? ei[e] : d;
    csr_src[row_ofs[d] + cnt2[(size_t)(s >> SLSHIFT) * N + d] + rank[e]] = s;
  }
}

// ---------------------------------------------------------------------------
// packed-fp16 score of one 8-channel chunk: sc += dot(leaky(x+xr), att)
__device__ __forceinline__ float score8(const H8 xv, const h2* __restrict__ xrh,
                                        const h2* __restrict__ ath, int q0,
                                        float sc) {
  const h2 slope = {(_Float16)NSLOPE, (_Float16)NSLOPE};
#pragma unroll
  for (int q = 0; q < 4; q++) {
    h2 v = xv.h[q] + xrh[q0 + q];
    h2 lk = __builtin_elementwise_max(v, v * slope);  // slope<1 => exact leaky
    sc = __builtin_amdgcn_fdot2(lk, ath[q0 + q], sc, false);
  }
  return sc;
}

// Edge accumulation (dual-edge ILP, split-2): returns softmax sum l,
// accumulates e*xl into acc[C].
template <int C>
__device__ __forceinline__ float edge_accumulate(
    const _Float16* __restrict__ xl, const int* __restrict__ csr_src,
    const h2* __restrict__ xrh, const h2* __restrict__ ath, int jb, int je,
    int p, int h, float* __restrict__ acc) {
  constexpr int Q = C / 8;
  float l = 0.f;
  int j = jb + p;
  for (; j + 2 < je; j += 4) {
    const int s0 = csr_src[j], s1 = csr_src[j + 2];
    const half8* xp0 = (const half8*)(xl + ((size_t)s0 * HEADS + h) * C);
    const half8* xp1 = (const half8*)(xl + ((size_t)s1 * HEADS + h) * C);
    H8 a[Q], b[Q];
#pragma unroll
    for (int q = 0; q < Q; q++) {
      a[q].v = xp0[q];
      b[q].v = xp1[q];
    }
    float sc0 = 0.f, sc1 = 0.f;
#pragma unroll
    for (int q = 0; q < Q; q++) {
      sc0 = score8(a[q], xrh, ath, 4 * q, sc0);
      sc1 = score8(b[q], xrh, ath, 4 * q, sc1);
    }
    const float e0 = __expf(sc0);
    const float e1 = __expf(sc1);
    l += e0 + e1;
#pragma unroll
    for (int q = 0; q < Q; q++)
#pragma unroll
      for (int k = 0; k < 4; k++) {
        const int c = 8 * q + 2 * k;
        acc[c + 0] = fmaf(e0, (float)a[q].h[k][0], acc[c + 0]);
        acc[c + 1] = fmaf(e0, (float)a[q].h[k][1], acc[c + 1]);
        acc[c + 0] = fmaf(e1, (float)b[q].h[k][0], acc[c + 0]);
        acc[c + 1] = fmaf(e1, (float)b[q].h[k][1], acc[c + 1]);
      }
  }
  for (; j < je; j += 2) {
    const int s = csr_src[j];
    const half8* xp = (const half8*)(xl + ((size_t)s * HEADS + h) * C);
    H8 a[Q];
#pragma unroll
    for (int q = 0; q < Q; q++) a[q].v = xp[q];
    float sc = 0.f;
#pragma unroll
    for (int q = 0; q < Q; q++) sc = score8(a[q], xrh, ath, 4 * q, sc);
    const float e = __expf(sc);
    l += e;
#pragma unroll
    for (int q = 0; q < Q; q++)
#pragma unroll
      for (int k = 0; k < 4; k++) {
        const int c = 8 * q + 2 * k;
        acc[c + 0] = fmaf(e, (float)a[q].h[k][0], acc[c + 0]);
        acc[c + 1] = fmaf(e, (float)a[q].h[k][1], acc[c + 1]);
      }
  }
  return l;
}

// Fused per-(node,head) no-max-softmax aggregation, split-2, degree-sorted.
// MODE 0: h = elu(agg + bias) stays in LDS; epilogue computes next layer's
//   GEMM via MFMA (B-fragments L2-direct), stages C into padded LDS, then
//   coalesced 16B stores (full lines, no RMW) — measured −5us net in R22.
// MODE 1: out fp32 [n*C + c] = mean_h(agg) + bias (8-lane butterfly).
template <int C, int MODE, int OUTC>
__global__ __launch_bounds__(256) void node_agg_kernel(
    const _Float16* __restrict__ xl, const _Float16* __restrict__ xr,
    const float* __restrict__ att, const float* __restrict__ bias,
    const int* __restrict__ row_ofs, const int* __restrict__ csr_src,
    const int* __restrict__ order, const _Float16* __restrict__ wtg,
    _Float16* __restrict__ oxl, _Float16* __restrict__ oxr,
    void* __restrict__ out, int N) {
  const int t = blockIdx.x * 256 + threadIdx.x;
  if constexpr (MODE == 0) {
    __shared__ _Float16 h_sh[32][72];        // this block's 32 h rows
    __shared__ _Float16 o_sh[32][OUTC + 8];  // staged epilogue output
    __shared__ int nid_sh[32];               // node ids of the 32 slots
    const int tl = threadIdx.x;
    if (tl < 32) {
      const int gs = blockIdx.x * 32 + tl;
      nid_sh[tl] = (gs < N) ? order[gs] : 0;
    }

    if (t < N * HEADS * 2) {
      const int n = order[t >> 3];
      const int h = t & 3;
      const int p = (t >> 2) & 1;
      h2 xrh[C / 2], ath[C / 2];
      {
        const h2* xrp = (const h2*)(xr + ((size_t)n * HEADS + h) * C);
        const float4* atp = (const float4*)(att + h * C);
#pragma unroll
        for (int q = 0; q < C / 2; q++) xrh[q] = xrp[q];
#pragma unroll
        for (int q = 0; q < C / 4; q++) {
          const float4 av = atp[q];
          ath[2 * q + 0] = h2{(_Float16)av.x, (_Float16)av.y};
          ath[2 * q + 1] = h2{(_Float16)av.z, (_Float16)av.w};
        }
      }
      float acc[C];
#pragma unroll
      for (int c = 0; c < C; c++) acc[c] = 0.f;
      float l = edge_accumulate<C>(xl, csr_src, xrh, ath, row_ofs[n],
                                   row_ofs[n + 1], p, h, acc);
      // merge split pair (partner lane = t ^ 4)
      l += __shfl_xor(l, 4);
#pragma unroll
      for (int c = 0; c < C; c++) acc[c] += __shfl_xor(acc[c], 4);
      const float inv_ = 1.f / l;
      const int c0 = p * (C / 2);  // this lane's 8 channels
      half8 hv;
#pragma unroll
      for (int c = 0; c < C / 2; c++) {
        const float v = fmaf(acc[c0 + c], inv_, bias[h * C + c0 + c]);
        hv[c] = (_Float16)(v > 0.f ? v : (__expf(v) - 1.f));
      }
      *(half8*)&h_sh[tl >> 3][h * 16 + p * 8] = hv;
    }
    __syncthreads();

    // Epilogue GEMM: [32 x 64] h_sh @ wt^T-layout -> OUTC combined cols.
    // B-fragments straight from global (L2-hot wt, coalesced per wave).
    const int lane = tl & 63, w = tl >> 6;
    const int lm = lane & 15, lq = lane >> 4;
    constexpr int CTW = OUTC / 16 / 4;  // col-tiles per wave
    constexpr int HC = OUTC / 2;        // per-matrix cols
#pragma unroll
    for (int ci = 0; ci < CTW; ci++) {
      const int ct = w * CTW + ci;
      const _Float16* wrow = wtg + ((size_t)(ct * 16 + lm) << 6);
      const half8 b0 = *(const half8*)(wrow + lq * 8);
      const half8 b1 = *(const half8*)(wrow + 32 + lq * 8);
#pragma unroll
      for (int mt = 0; mt < 2; mt++) {
        const half8 a0 = *(const half8*)&h_sh[mt * 16 + lm][lq * 8];
        const half8 a1 = *(const half8*)&h_sh[mt * 16 + lm][32 + lq * 8];
        f32x4 cacc = {0.f, 0.f, 0.f, 0.f};
        cacc = __builtin_amdgcn_mfma_f32_16x16x32_f16(a0, b0, cacc, 0, 0, 0);
        cacc = __builtin_amdgcn_mfma_f32_16x16x32_f16(a1, b1, cacc, 0, 0, 0);
        const int cn = ct * 16 + lm;
#pragma unroll
        for (int r = 0; r < 4; r++)
          o_sh[mt * 16 + lq * 4 + r][cn] = (_Float16)cacc[r];
      }
    }
    __syncthreads();

    // Coalesced write-out: 32 slots x (OUTC/8) half8-chunks.
    constexpr int CPT = 32 * (OUTC / 8) / 256;  // chunks per thread
    constexpr int HC8 = HC / 8;
#pragma unroll
    for (int k = 0; k < CPT; k++) {
      const int c = tl + k * 256;
      const int slot = c / (OUTC / 8), col8 = c % (OUTC / 8);
      if (blockIdx.x * 32 + slot < N) {
        const half8 v = *(const half8*)&o_sh[slot][col8 * 8];
        const int nO = nid_sh[slot];
        if (col8 < HC8)
          *(half8*)(oxl + (size_t)nO * HC + col8 * 8) = v;
        else
          *(half8*)(oxr + (size_t)nO * HC + (col8 - HC8) * 8) = v;
      }
    }
  } else {
    if (t >= N * HEADS * 2) return;
    const int n = order[t >> 3];
    const int h = t & 3;
    const int p = (t >> 2) & 1;
    h2 xrh[C / 2], ath[C / 2];
    {
      const h2* xrp = (const h2*)(xr + ((size_t)n * HEADS + h) * C);
      const float4* atp = (const float4*)(att + h * C);
#pragma unroll
      for (int q = 0; q < C / 2; q++) xrh[q] = xrp[q];
#pragma unroll
      for (int q = 0; q < C / 4; q++) {
        const float4 av = atp[q];
        ath[2 * q + 0] = h2{(_Float16)av.x, (_Float16)av.y};
        ath[2 * q + 1] = h2{(_Float16)av.z, (_Float16)av.w};
      }
    }
    float acc[C];
#pragma unroll
    for (int c = 0; c < C; c++) acc[c] = 0.f;
    float l = edge_accumulate<C>(xl, csr_src, xrh, ath, row_ofs[n],
                                 row_ofs[n + 1], p, h, acc);
    l += __shfl_xor(l, 4);
#pragma unroll
    for (int c = 0; c < C; c++) acc[c] += __shfl_xor(acc[c], 4);
    const float inv_ = 1.f / l;
    // head-mean butterfly over h bits (lanes ^1, ^2)
    float* o = (float*)out;
#pragma unroll
    for (int c = 0; c < C; c++) {
      float v = acc[c] * inv_;
      v += __shfl_xor(v, 1);
      v += __shfl_xor(v, 2);
      acc[c] = v * 0.25f;
    }
    const int il = t & 7;         // lane-in-node
    const int c0 = il * (C / 8);  // C=32: 4 channels per lane
    float4 ob;
    ob.x = acc[c0 + 0] + bias[c0 + 0];
    ob.y = acc[c0 + 1] + bias[c0 + 1];
    ob.z = acc[c0 + 2] + bias[c0 + 2];
    ob.w = acc[c0 + 3] + bias[c0 + 3];
    *(float4*)(o + (size_t)n * C + c0) = ob;
  }
}

// ---------------------------------------------------------------------------
extern "C" void kernel_launch(void* const* d_in, const int* in_sizes, int n_in,
                              void* d_out, int out_size, void* d_ws,
                              size_t ws_size, hipStream_t stream) {
  const float* x = (const float*)d_in[0];
  const int* ei = (const int*)d_in[1];
  const float* W1l = (const float*)d_in[2];
  const float* W1r = (const float*)d_in[3];
  const float* a1 = (const float*)d_in[4];
  const float* b1 = (const float*)d_in[5];
  const float* W2l = (const float*)d_in[6];
  const float* W2r = (const float*)d_in[7];
  const float* a2 = (const float*)d_in[8];
  const float* b2 = (const float*)d_in[9];
  const float* W3l = (const float*)d_in[10];
  const float* W3r = (const float*)d_in[11];
  const float* a3 = (const float*)d_in[12];
  const float* b3 = (const float*)d_in[13];

  const int N = in_sizes[0] / 64;
  const int E = in_sizes[1] / 2;
  const int ET = E + N;
  const int NS = ((N - 1) >> SLSHIFT) + 1;  // source slices (N=100k -> 13)

  char* ws = (char*)d_ws;
  const size_t szQ = (size_t)N * 64 * sizeof(_Float16);  // 12.8 MB
  // bufA [0, 4Q): xl1/xr1 (layer-1 features), later xl3/xr3 (layer-3)
  _Float16* xl1 = (_Float16*)ws;
  _Float16* xr1 = (_Float16*)(ws + szQ);
  _Float16* xl3 = (_Float16*)ws;              // aliases dead xl1/xr1
  _Float16* xr3 = (_Float16*)(ws + 2 * szQ);
  // bufB [4Q, 6Q): xl2/xr2 (layer-2 features)
  _Float16* xl2 = (_Float16*)(ws + 4 * szQ);
  _Float16* xr2 = (_Float16*)(ws + 5 * szQ);
  char* p = ws + 6 * szQ;
  int* deg = (int*)p;                                  p += (size_t)N * 4;
  int* row_ofs = (int*)p;                              p += (size_t)(N + 1) * 4;
  int* bsums = (int*)p;                                p += 128 * 4;
  int* hist = (int*)p;                                 p += 64 * 4;
  int* cursor2 = (int*)p;                              p += 64 * 4;
  int* order = (int*)p;                                p += (size_t)N * 4;
  p = (char*)(((uintptr_t)p + 15) & ~(uintptr_t)15);
  int* rank = (int*)p;                                 p += (size_t)ET * 4;
  p = (char*)(((uintptr_t)p + 15) & ~(uintptr_t)15);
  int* csr_src = (int*)p;                              p += (size_t)ET * 4;
  p = (char*)(((uintptr_t)p + 15) & ~(uintptr_t)15);
  _Float16* wt1 = (_Float16*)p;                        p += 8192 * 2;
  _Float16* wt2 = (_Float16*)p;                        p += 8192 * 2;
  _Float16* wt3 = (_Float16*)p;                        p += 16384 * 2;
  p = (char*)(((uintptr_t)p + 15) & ~(uintptr_t)15);
  int* cnt2 = (int*)p;                                 p += (size_t)N * NS * 4;

  const int edgeBlocks = (ET + 255) / 256;
  const int nodeBlocks = (N + 255) / 256;
  const int nh2Blocks = (N * HEADS * 2 + 255) / 256;
  const int rowBlocks = (N + 63) / 64;
  const int scanBlocks = (N + 1023) / 1024;  // 98 <= 128
  const int nSlice = (N + 7) / 8;

  // ---- preamble + layer-1 GEMM (fused/overlapped), R19b structure ----
  wt_build_zero_kernel<<<512, 256, 0, stream>>>(W1l, W1r, W2l, W2r, W3l, W3r,
                                                wt1, wt2, wt3, cnt2, hist,
                                                cursor2, N * NS);
  gemm1_count_kernel<<<rowBlocks + edgeBlocks, 256, 0, stream>>>(
      x, wt1, xl1, xr1, ei, E, ET, N, cnt2, rank, rowBlocks);
  slicescan_kernel<<<scanBlocks, 256, 0, stream>>>(cnt2, deg, row_ofs, bsums,
                                                   hist, N, NS);
  finalize2_kernel<<<nodeBlocks, 256, 0, stream>>>(
      row_ofs, bsums, deg, hist, cursor2, order, N, ET, scanBlocks);
  fill_kernel<<<8 * 96, 256, 0, stream>>>(ei, rank, row_ofs, cnt2, E, ET, N,
                                          nSlice, csr_src);

  // ---- Layer 1 agg + fused layer-2 GEMM ----
  node_agg_kernel<16, 0, 128><<<nh2Blocks, 256, 0, stream>>>(
      xl1, xr1, a1, b1, row_ofs, csr_src, order, wt2, xl2, xr2, nullptr, N);
  // ---- Layer 2 agg + fused layer-3 GEMM ----
  node_agg_kernel<16, 0, 256><<<nh2Blocks, 256, 0, stream>>>(
      xl2, xr2, a2, b2, row_ofs, csr_src, order, wt3, xl3, xr3, nullptr, N);
  // ---- Layer 3 agg: mean over heads -> output ----
  node_agg_kernel<32, 1, 16><<<nh2Blocks, 256, 0, stream>>>(
      xl3, xr3, a3, b3, row_ofs, csr_src, order, nullptr, nullptr, nullptr,
      d_out, N);
}

// Round 14
// 308.379 us; speedup vs baseline: 1.0240x; 1.0240x over previous
//
#include <hip/hip_runtime.h>
#include <math.h>

// GATv2 3-layer forward, MI355X.
// R26 = R24 exact revert (measured best, 308.5us). R25's LDS-free gemm1
// raised occupancy 35->45% but REGRESSED dur (53->57, total +7): gemm1_count
// is not occupancy-limited; the count scatter-atomic chain is a latency
// floor (ILP/occupancy/placement variants all measured worse: R20/R23/R25),
// and the gemm side is best LDS-staged. Final configuration; every component
// is the winner of a within-session A/B:
//  - R19b fused preamble (gemm1||count, slicescan, finalize2, XCD fill)
//  - single-edge rank-capturing count (beats 4-edge ILP, fire-and-forget)
//  - LDS-staged gemm1 with direct fragment writes (beats osh / LDS-free)
//  - slice-sorted CSR (SLSHIFT=13) for agg gather locality (59.5->54.5)
//  - dual-edge split-2 no-max-softmax agg, degree-sorted (R7/R10/R14)
//  - GEMM-in-epilogue (h never hits HBM; L2-direct B-frags; o_sh coalesced
//    stores, -5us measured in R22)
// Session: 323.1 -> 308.5us. Residual = random-gather wall (~2.5TB/s,
// MLP x TLP invariant) + latency-bound CSR build.
// N=100000, E=800000 (+N self loops), Fin=64, H=4, C=16/16/32.

#define HEADS 4
#define NSLOPE 0.2f
#define SLSHIFT 13  // source-slice = 8192 nodes (2MB of layer-3 xl rows)

typedef __attribute__((ext_vector_type(8))) _Float16 half8;
typedef __attribute__((ext_vector_type(2))) _Float16 h2;
typedef __attribute__((ext_vector_type(4))) float f32x4;

union H8 {
  half8 v;
  h2 h[4];
};

// ---------------------------------------------------------------------------
// K1: build fp16 W^T for all 3 layers (wt[c*64+k] = W[k][c], combined
// [Wl | Wr] cols) + zero cnt2/hist/cursor2.
__global__ __launch_bounds__(256) void wt_build_zero_kernel(
    const float* __restrict__ W1l, const float* __restrict__ W1r,
    const float* __restrict__ W2l, const float* __restrict__ W2r,
    const float* __restrict__ W3l, const float* __restrict__ W3r,
    _Float16* __restrict__ wt1, _Float16* __restrict__ wt2,
    _Float16* __restrict__ wt3, int* __restrict__ cnt2, int* __restrict__ hist,
    int* __restrict__ cursor2, int NZ) {
  const int tid = blockIdx.x * 256 + threadIdx.x;
  for (int i = tid; i < NZ; i += gridDim.x * 256) cnt2[i] = 0;
  if (tid < 64) {
    hist[tid] = 0;
    cursor2[tid] = 0;
  }
  int i = tid;
  const float *Wl, *Wr;
  _Float16* wt;
  int COLS;
  if (i < 8192) {
    Wl = W1l; Wr = W1r; wt = wt1; COLS = 64;
  } else if (i < 16384) {
    i -= 8192; Wl = W2l; Wr = W2r; wt = wt2; COLS = 64;
  } else if (i < 32768) {
    i -= 16384; Wl = W3l; Wr = W3r; wt = wt3; COLS = 128;
  } else {
    return;
  }
  const int c = i >> 6, k = i & 63;
  const float v = (c < COLS) ? Wl[k * COLS + c] : Wr[k * COLS + (c - COLS)];
  wt[i] = (_Float16)v;
}

// ---------------------------------------------------------------------------
// MFMA GEMM body (layer 1: 128 combined cols, fp32 input): [xl|xr] =
// in @ [Wl|Wr], K=64, mfma_f32_16x16x32_f16, 64 rows x 128 cols, 4 waves.
// A-frag: A[m=lane&15][k=quad*8+j]; B-frag: B[k=quad*8+j][n=lane&15];
// C/D: col=lane&15, row=quad*4+reg (m89-verified mapping).
// LDS-staged, direct fragment writes (R24 measured-best form).
__device__ __forceinline__ void gemm_body(const float* __restrict__ inf,
                                          const _Float16* __restrict__ wt,
                                          _Float16* __restrict__ xl,
                                          _Float16* __restrict__ xr, int N,
                                          int bx) {
  __shared__ _Float16 xsh[64][72];   // A tile [m][k]
  __shared__ _Float16 bsh[128][72];  // B tile [n][k] (wt)
  const int row0 = bx * 64;
  const int t = threadIdx.x;

  // stage A: thread owns row t&63, k-range (t>>6)*16..+15 (fp32 -> fp16)
  {
    const int r = t & 63, kq = t >> 6;
    const int row = row0 + r;
    half8 h0, h1;
    if (row < N) {
      const float4* src = (const float4*)(inf + (size_t)row * 64 + kq * 16);
      const float4 q0 = src[0], q1 = src[1], q2 = src[2], q3 = src[3];
      h0[0] = (_Float16)q0.x; h0[1] = (_Float16)q0.y;
      h0[2] = (_Float16)q0.z; h0[3] = (_Float16)q0.w;
      h0[4] = (_Float16)q1.x; h0[5] = (_Float16)q1.y;
      h0[6] = (_Float16)q1.z; h0[7] = (_Float16)q1.w;
      h1[0] = (_Float16)q2.x; h1[1] = (_Float16)q2.y;
      h1[2] = (_Float16)q2.z; h1[3] = (_Float16)q2.w;
      h1[4] = (_Float16)q3.x; h1[5] = (_Float16)q3.y;
      h1[6] = (_Float16)q3.z; h1[7] = (_Float16)q3.w;
    } else {
#pragma unroll
      for (int j = 0; j < 8; j++) {
        h0[j] = (_Float16)0.f;
        h1[j] = (_Float16)0.f;
      }
    }
    *(half8*)&xsh[r][kq * 16] = h0;
    *(half8*)&xsh[r][kq * 16 + 8] = h1;
  }
  // stage B: 128 wt rows x 64 halves; thread t copies 32 halves of row t>>1
  {
    const int rr = t >> 1, hh = t & 1;
    const half8* src = (const half8*)(wt + ((size_t)rr << 6) + hh * 32);
    const half8 b0 = src[0], b1 = src[1], b2 = src[2], b3 = src[3];
    half8* dst = (half8*)&bsh[rr][hh * 32];
    dst[0] = b0; dst[1] = b1; dst[2] = b2; dst[3] = b3;
  }
  __syncthreads();

  const int lane = t & 63, w = t >> 6;
  const int lm = lane & 15, lq = lane >> 4;
  const int m0 = w * 16;
  const half8 a0 = *(const half8*)&xsh[m0 + lm][lq * 8];
  const half8 a1 = *(const half8*)&xsh[m0 + lm][32 + lq * 8];
  f32x4 acc[8];
#pragma unroll
  for (int nt = 0; nt < 8; nt++) {
    const half8 b0 = *(const half8*)&bsh[nt * 16 + lm][lq * 8];
    const half8 b1 = *(const half8*)&bsh[nt * 16 + lm][32 + lq * 8];
    f32x4 c = {0.f, 0.f, 0.f, 0.f};
    c = __builtin_amdgcn_mfma_f32_16x16x32_f16(a0, b0, c, 0, 0, 0);
    c = __builtin_amdgcn_mfma_f32_16x16x32_f16(a1, b1, c, 0, 0, 0);
    acc[nt] = c;
  }

  const int rbase = row0 + m0 + lq * 4;
#pragma unroll
  for (int nt = 0; nt < 8; nt++) {
    const int cn = nt * 16 + lm;  // combined col (branch wave-uniform)
    if (cn < 64) {
#pragma unroll
      for (int r = 0; r < 4; r++)
        if (rbase + r < N)
          xl[(size_t)(rbase + r) * 64 + cn] = (_Float16)acc[nt][r];
    } else {
      const int cx = cn - 64;
#pragma unroll
      for (int r = 0; r < 4; r++)
        if (rbase + r < N)
          xr[(size_t)(rbase + r) * 64 + cx] = (_Float16)acc[nt][r];
    }
  }
}

// ---------------------------------------------------------------------------
// count body (R21 form): per-(dst, src-slice) count, capturing per-edge rank
// WITHIN the slice bucket. cnt2 layout [NS][N] (transposed).
__device__ __forceinline__ void count_body(const int* __restrict__ ei, int E,
                                           int ET, int N,
                                           int* __restrict__ cnt2,
                                           int* __restrict__ rank, int e) {
  if (e >= ET) return;
  const int d = (e < E) ? ei[E + e] : (e - E);
  const int s = (e < E) ? ei[e] : d;
  rank[e] = atomicAdd(cnt2 + (size_t)(s >> SLSHIFT) * N + d, 1);
}

// K2: fused gemm1 (blocks [0,GB)) + count (blocks [GB, GB+edgeBlocks)).
__global__ __launch_bounds__(256) void gemm1_count_kernel(
    const float* __restrict__ x, const _Float16* __restrict__ wt1,
    _Float16* __restrict__ xl, _Float16* __restrict__ xr,
    const int* __restrict__ ei, int E, int ET, int N, int* __restrict__ cnt2,
    int* __restrict__ rank, int GB) {
  if ((int)blockIdx.x < GB) {
    gemm_body(x, wt1, xl, xr, N, blockIdx.x);
  } else {
    count_body(ei, E, ET, N, cnt2, rank,
               ((int)blockIdx.x - GB) * 256 + (int)threadIdx.x);
  }
}

// ---------------------------------------------------------------------------
// K3: fused slice-offset scan + degree output + block prefix scan + degree
// histogram. Per block: 1024 nodes (int4/thread). Writes per-block exclusive
// prefix into row_ofs (block base added in finalize2).
__global__ __launch_bounds__(256) void slicescan_kernel(
    int* __restrict__ cnt2, int* __restrict__ deg, int* __restrict__ pre,
    int* __restrict__ bsums, int* __restrict__ hist, int N, int NS) {
  __shared__ int lh[64];
  __shared__ int wsum[4];
  const int t = threadIdx.x;
  if (t < 64) lh[t] = 0;
  __syncthreads();
  const int i0 = blockIdx.x * 1024 + t * 4;
  int4 v;  // degrees of the 4 owned nodes
  if (i0 + 3 < N) {
    int rx = 0, ry = 0, rz = 0, rw = 0;
    for (int k = 0; k < NS; k++) {
      int* pp = cnt2 + (size_t)k * N + i0;
      const int4 c = *(const int4*)pp;
      int4 o; o.x = rx; o.y = ry; o.z = rz; o.w = rw;
      *(int4*)pp = o;
      rx += c.x; ry += c.y; rz += c.z; rw += c.w;
    }
    v.x = rx; v.y = ry; v.z = rz; v.w = rw;
    *(int4*)(deg + i0) = v;
    atomicAdd(&lh[min(v.x, 63)], 1);
    atomicAdd(&lh[min(v.y, 63)], 1);
    atomicAdd(&lh[min(v.z, 63)], 1);
    atomicAdd(&lh[min(v.w, 63)], 1);
  } else {
    int rr[4] = {0, 0, 0, 0};
    for (int e2 = 0; e2 < 4; e2++) {
      const int idx = i0 + e2;
      if (idx < N) {
        int run = 0;
        for (int k = 0; k < NS; k++) {
          int* pp = cnt2 + (size_t)k * N + idx;
          const int c = *pp;
          *pp = run;
          run += c;
        }
        deg[idx] = run;
        rr[e2] = run;
        atomicAdd(&lh[min(run, 63)], 1);
      }
    }
    v.x = rr[0]; v.y = rr[1]; v.z = rr[2]; v.w = rr[3];
  }
  const int s = v.x + v.y + v.z + v.w;
  const int lane = t & 63, wave = t >> 6;
  int x = s;
#pragma unroll
  for (int off = 1; off < 64; off <<= 1) {
    const int y = __shfl_up(x, off);
    if (lane >= off) x += y;
  }
  if (lane == 63) wsum[wave] = x;
  __syncthreads();
  int wbase = 0;
#pragma unroll
  for (int w = 0; w < 3; w++)
    if (w < wave) wbase += wsum[w];
  const int ex = wbase + (x - s);
  if (i0 + 3 < N) {
    int4 o;
    o.x = ex;
    o.y = ex + v.x;
    o.z = o.y + v.y;
    o.w = o.z + v.z;
    *(int4*)(pre + i0) = o;
  } else {
    int run = ex;
    if (i0 + 0 < N) pre[i0 + 0] = run;
    run += v.x;
    if (i0 + 1 < N) pre[i0 + 1] = run;
    run += v.y;
    if (i0 + 2 < N) pre[i0 + 2] = run;
    run += v.z;
    if (i0 + 3 < N) pre[i0 + 3] = run;
  }
  if (t == 255) bsums[blockIdx.x] = wbase + x;  // block total
  if (t < 64 && lh[t] > 0) atomicAdd(hist + t, lh[t]);
}

// ---------------------------------------------------------------------------
// K4: finalize with scan2 folded in (cursor2 = cross-block bin cursor).
// row_ofs[i] += block base (slicescan wrote the per-block prefix).
__global__ __launch_bounds__(256) void finalize2_kernel(
    int* __restrict__ row_ofs, const int* __restrict__ bsums,
    const int* __restrict__ deg, const int* __restrict__ hist,
    int* __restrict__ cursor2, int* __restrict__ order, int N, int ET, int B) {
  __shared__ int sbs[128];
  __shared__ int ws0s;
  __shared__ int lh[64];
  __shared__ int base[64];
  const int t = threadIdx.x;
  int xv = 0, vv = 0;
  if (t < 128) {
    const int lane = t & 63;
    vv = (t < B) ? bsums[t] : 0;
    xv = vv;
#pragma unroll
    for (int off = 1; off < 64; off <<= 1) {
      const int y = __shfl_up(xv, off);
      if (lane >= off) xv += y;
    }
    if (t == 63) ws0s = xv;
  }
  if (t < 64) lh[t] = 0;
  __syncthreads();
  if (t < 128) sbs[t] = ((t >> 6) ? ws0s : 0) + xv - vv;  // exclusive
  __syncthreads();

  const int i = blockIdx.x * 256 + t;
  const int q = blockIdx.x >> 2;  // 256-node block -> constant 1024-chunk id
  if (i == 0) row_ofs[N] = ET;
  int b = 0, r = 0;
  if (i < N) {
    row_ofs[i] += sbs[q];
    b = min(deg[i], 63);
    r = atomicAdd(&lh[b], 1);
  }
  __syncthreads();
  if (t < 64) {
    const int bin = 63 - t;  // lane order = descending degree bins
    const int rv = hist[bin];
    int xx = rv;
#pragma unroll
    for (int off = 1; off < 64; off <<= 1) {
      const int y = __shfl_up(xx, off);
      if (t >= off) xx += y;
    }
    int bb = xx - rv;  // exclusive sum of higher-degree bins
    const int cnt = lh[bin];
    if (cnt > 0) bb += atomicAdd(cursor2 + bin, cnt);
    base[bin] = bb;
  }
  __syncthreads();
  if (i < N) order[base[b] + r] = i;
}

// XCD-sliced CSR fill (slice-sorted positions via cnt2 base + rank).
__global__ __launch_bounds__(256) void fill_kernel(
    const int* __restrict__ ei, const int* __restrict__ rank,
    const int* __restrict__ row_ofs, const int* __restrict__ cnt2, int E,
    int ET, int N, int nSlice, int* __restrict__ csr_src) {
  const int xcd = blockIdx.x & 7;
  const int bId = blockIdx.x >> 3;
  const int nB = gridDim.x >> 3;
  const int dlo = xcd * nSlice, dhi = dlo + nSlice;
  for (int e = bId * 256 + threadIdx.x; e < ET; e += nB * 256) {
    const int d = (e < E) ? ei[E + e] : (e - E);
    if (d < dlo || d >= dhi) continue;
    const int s = (e < E) ? ei[e] : d;
    csr_src[row_ofs[d] + cnt2[(size_t)(s >> SLSHIFT) * N + d] + rank[e]] = s;
  }
}

// ---------------------------------------------------------------------------
// packed-fp16 score of one 8-channel chunk: sc += dot(leaky(x+xr), att)
__device__ __forceinline__ float score8(const H8 xv, const h2* __restrict__ xrh,
                                        const h2* __restrict__ ath, int q0,
                                        float sc) {
  const h2 slope = {(_Float16)NSLOPE, (_Float16)NSLOPE};
#pragma unroll
  for (int q = 0; q < 4; q++) {
    h2 v = xv.h[q] + xrh[q0 + q];
    h2 lk = __builtin_elementwise_max(v, v * slope);  // slope<1 => exact leaky
    sc = __builtin_amdgcn_fdot2(lk, ath[q0 + q], sc, false);
  }
  return sc;
}

// Edge accumulation (dual-edge ILP, split-2): returns softmax sum l,
// accumulates e*xl into acc[C].
template <int C>
__device__ __forceinline__ float edge_accumulate(
    const _Float16* __restrict__ xl, const int* __restrict__ csr_src,
    const h2* __restrict__ xrh, const h2* __restrict__ ath, int jb, int je,
    int p, int h, float* __restrict__ acc) {
  constexpr int Q = C / 8;
  float l = 0.f;
  int j = jb + p;
  for (; j + 2 < je; j += 4) {
    const int s0 = csr_src[j], s1 = csr_src[j + 2];
    const half8* xp0 = (const half8*)(xl + ((size_t)s0 * HEADS + h) * C);
    const half8* xp1 = (const half8*)(xl + ((size_t)s1 * HEADS + h) * C);
    H8 a[Q], b[Q];
#pragma unroll
    for (int q = 0; q < Q; q++) {
      a[q].v = xp0[q];
      b[q].v = xp1[q];
    }
    float sc0 = 0.f, sc1 = 0.f;
#pragma unroll
    for (int q = 0; q < Q; q++) {
      sc0 = score8(a[q], xrh, ath, 4 * q, sc0);
      sc1 = score8(b[q], xrh, ath, 4 * q, sc1);
    }
    const float e0 = __expf(sc0);
    const float e1 = __expf(sc1);
    l += e0 + e1;
#pragma unroll
    for (int q = 0; q < Q; q++)
#pragma unroll
      for (int k = 0; k < 4; k++) {
        const int c = 8 * q + 2 * k;
        acc[c + 0] = fmaf(e0, (float)a[q].h[k][0], acc[c + 0]);
        acc[c + 1] = fmaf(e0, (float)a[q].h[k][1], acc[c + 1]);
        acc[c + 0] = fmaf(e1, (float)b[q].h[k][0], acc[c + 0]);
        acc[c + 1] = fmaf(e1, (float)b[q].h[k][1], acc[c + 1]);
      }
  }
  for (; j < je; j += 2) {
    const int s = csr_src[j];
    const half8* xp = (const half8*)(xl + ((size_t)s * HEADS + h) * C);
    H8 a[Q];
#pragma unroll
    for (int q = 0; q < Q; q++) a[q].v = xp[q];
    float sc = 0.f;
#pragma unroll
    for (int q = 0; q < Q; q++) sc = score8(a[q], xrh, ath, 4 * q, sc);
    const float e = __expf(sc);
    l += e;
#pragma unroll
    for (int q = 0; q < Q; q++)
#pragma unroll
      for (int k = 0; k < 4; k++) {
        const int c = 8 * q + 2 * k;
        acc[c + 0] = fmaf(e, (float)a[q].h[k][0], acc[c + 0]);
        acc[c + 1] = fmaf(e, (float)a[q].h[k][1], acc[c + 1]);
      }
  }
  return l;
}

// Fused per-(node,head) no-max-softmax aggregation, split-2, degree-sorted.
// MODE 0: h = elu(agg + bias) stays in LDS; epilogue computes next layer's
//   GEMM via MFMA (B-fragments L2-direct), stages C into padded LDS, then
//   coalesced 16B stores (full lines, no RMW) — measured −5us net in R22.
// MODE 1: out fp32 [n*C + c] = mean_h(agg) + bias (8-lane butterfly).
template <int C, int MODE, int OUTC>
__global__ __launch_bounds__(256) void node_agg_kernel(
    const _Float16* __restrict__ xl, const _Float16* __restrict__ xr,
    const float* __restrict__ att, const float* __restrict__ bias,
    const int* __restrict__ row_ofs, const int* __restrict__ csr_src,
    const int* __restrict__ order, const _Float16* __restrict__ wtg,
    _Float16* __restrict__ oxl, _Float16* __restrict__ oxr,
    void* __restrict__ out, int N) {
  const int t = blockIdx.x * 256 + threadIdx.x;
  if constexpr (MODE == 0) {
    __shared__ _Float16 h_sh[32][72];        // this block's 32 h rows
    __shared__ _Float16 o_sh[32][OUTC + 8];  // staged epilogue output
    __shared__ int nid_sh[32];               // node ids of the 32 slots
    const int tl = threadIdx.x;
    if (tl < 32) {
      const int gs = blockIdx.x * 32 + tl;
      nid_sh[tl] = (gs < N) ? order[gs] : 0;
    }

    if (t < N * HEADS * 2) {
      const int n = order[t >> 3];
      const int h = t & 3;
      const int p = (t >> 2) & 1;
      h2 xrh[C / 2], ath[C / 2];
      {
        const h2* xrp = (const h2*)(xr + ((size_t)n * HEADS + h) * C);
        const float4* atp = (const float4*)(att + h * C);
#pragma unroll
        for (int q = 0; q < C / 2; q++) xrh[q] = xrp[q];
#pragma unroll
        for (int q = 0; q < C / 4; q++) {
          const float4 av = atp[q];
          ath[2 * q + 0] = h2{(_Float16)av.x, (_Float16)av.y};
          ath[2 * q + 1] = h2{(_Float16)av.z, (_Float16)av.w};
        }
      }
      float acc[C];
#pragma unroll
      for (int c = 0; c < C; c++) acc[c] = 0.f;
      float l = edge_accumulate<C>(xl, csr_src, xrh, ath, row_ofs[n],
                                   row_ofs[n + 1], p, h, acc);
      // merge split pair (partner lane = t ^ 4)
      l += __shfl_xor(l, 4);
#pragma unroll
      for (int c = 0; c < C; c++) acc[c] += __shfl_xor(acc[c], 4);
      const float inv_ = 1.f / l;
      const int c0 = p * (C / 2);  // this lane's 8 channels
      half8 hv;
#pragma unroll
      for (int c = 0; c < C / 2; c++) {
        const float v = fmaf(acc[c0 + c], inv_, bias[h * C + c0 + c]);
        hv[c] = (_Float16)(v > 0.f ? v : (__expf(v) - 1.f));
      }
      *(half8*)&h_sh[tl >> 3][h * 16 + p * 8] = hv;
    }
    __syncthreads();

    // Epilogue GEMM: [32 x 64] h_sh @ wt^T-layout -> OUTC combined cols.
    // B-fragments straight from global (L2-hot wt, coalesced per wave).
    const int lane = tl & 63, w = tl >> 6;
    const int lm = lane & 15, lq = lane >> 4;
    constexpr int CTW = OUTC / 16 / 4;  // col-tiles per wave
    constexpr int HC = OUTC / 2;        // per-matrix cols
#pragma unroll
    for (int ci = 0; ci < CTW; ci++) {
      const int ct = w * CTW + ci;
      const _Float16* wrow = wtg + ((size_t)(ct * 16 + lm) << 6);
      const half8 b0 = *(const half8*)(wrow + lq * 8);
      const half8 b1 = *(const half8*)(wrow + 32 + lq * 8);
#pragma unroll
      for (int mt = 0; mt < 2; mt++) {
        const half8 a0 = *(const half8*)&h_sh[mt * 16 + lm][lq * 8];
        const half8 a1 = *(const half8*)&h_sh[mt * 16 + lm][32 + lq * 8];
        f32x4 cacc = {0.f, 0.f, 0.f, 0.f};
        cacc = __builtin_amdgcn_mfma_f32_16x16x32_f16(a0, b0, cacc, 0, 0, 0);
        cacc = __builtin_amdgcn_mfma_f32_16x16x32_f16(a1, b1, cacc, 0, 0, 0);
        const int cn = ct * 16 + lm;
#pragma unroll
        for (int r = 0; r < 4; r++)
          o_sh[mt * 16 + lq * 4 + r][cn] = (_Float16)cacc[r];
      }
    }
    __syncthreads();

    // Coalesced write-out: 32 slots x (OUTC/8) half8-chunks.
    constexpr int CPT = 32 * (OUTC / 8) / 256;  // chunks per thread
    constexpr int HC8 = HC / 8;
#pragma unroll
    for (int k = 0; k < CPT; k++) {
      const int c = tl + k * 256;
      const int slot = c / (OUTC / 8), col8 = c % (OUTC / 8);
      if (blockIdx.x * 32 + slot < N) {
        const half8 v = *(const half8*)&o_sh[slot][col8 * 8];
        const int nO = nid_sh[slot];
        if (col8 < HC8)
          *(half8*)(oxl + (size_t)nO * HC + col8 * 8) = v;
        else
          *(half8*)(oxr + (size_t)nO * HC + (col8 - HC8) * 8) = v;
      }
    }
  } else {
    if (t >= N * HEADS * 2) return;
    const int n = order[t >> 3];
    const int h = t & 3;
    const int p = (t >> 2) & 1;
    h2 xrh[C / 2], ath[C / 2];
    {
      const h2* xrp = (const h2*)(xr + ((size_t)n * HEADS + h) * C);
      const float4* atp = (const float4*)(att + h * C);
#pragma unroll
      for (int q = 0; q < C / 2; q++) xrh[q] = xrp[q];
#pragma unroll
      for (int q = 0; q < C / 4; q++) {
        const float4 av = atp[q];
        ath[2 * q + 0] = h2{(_Float16)av.x, (_Float16)av.y};
        ath[2 * q + 1] = h2{(_Float16)av.z, (_Float16)av.w};
      }
    }
    float acc[C];
#pragma unroll
    for (int c = 0; c < C; c++) acc[c] = 0.f;
    float l = edge_accumulate<C>(xl, csr_src, xrh, ath, row_ofs[n],
                                 row_ofs[n + 1], p, h, acc);
    l += __shfl_xor(l, 4);
#pragma unroll
    for (int c = 0; c < C; c++) acc[c] += __shfl_xor(acc[c], 4);
    const float inv_ = 1.f / l;
    // head-mean butterfly over h bits (lanes ^1, ^2)
    float* o = (float*)out;
#pragma unroll
    for (int c = 0; c < C; c++) {
      float v = acc[c] * inv_;
      v += __shfl_xor(v, 1);
      v += __shfl_xor(v, 2);
      acc[c] = v * 0.25f;
    }
    const int il = t & 7;         // lane-in-node
    const int c0 = il * (C / 8);  // C=32: 4 channels per lane
    float4 ob;
    ob.x = acc[c0 + 0] + bias[c0 + 0];
    ob.y = acc[c0 + 1] + bias[c0 + 1];
    ob.z = acc[c0 + 2] + bias[c0 + 2];
    ob.w = acc[c0 + 3] + bias[c0 + 3];
    *(float4*)(o + (size_t)n * C + c0) = ob;
  }
}

// ---------------------------------------------------------------------------
extern "C" void kernel_launch(void* const* d_in, const int* in_sizes, int n_in,
                              void* d_out, int out_size, void* d_ws,
                              size_t ws_size, hipStream_t stream) {
  const float* x = (const float*)d_in[0];
  const int* ei = (const int*)d_in[1];
  const float* W1l = (const float*)d_in[2];
  const float* W1r = (const float*)d_in[3];
  const float* a1 = (const float*)d_in[4];
  const float* b1 = (const float*)d_in[5];
  const float* W2l = (const float*)d_in[6];
  const float* W2r = (const float*)d_in[7];
  const float* a2 = (const float*)d_in[8];
  const float* b2 = (const float*)d_in[9];
  const float* W3l = (const float*)d_in[10];
  const float* W3r = (const float*)d_in[11];
  const float* a3 = (const float*)d_in[12];
  const float* b3 = (const float*)d_in[13];

  const int N = in_sizes[0] / 64;
  const int E = in_sizes[1] / 2;
  const int ET = E + N;
  const int NS = ((N - 1) >> SLSHIFT) + 1;  // source slices (N=100k -> 13)

  char* ws = (char*)d_ws;
  const size_t szQ = (size_t)N * 64 * sizeof(_Float16);  // 12.8 MB
  // bufA [0, 4Q): xl1/xr1 (layer-1 features), later xl3/xr3 (layer-3)
  _Float16* xl1 = (_Float16*)ws;
  _Float16* xr1 = (_Float16*)(ws + szQ);
  _Float16* xl3 = (_Float16*)ws;              // aliases dead xl1/xr1
  _Float16* xr3 = (_Float16*)(ws + 2 * szQ);
  // bufB [4Q, 6Q): xl2/xr2 (layer-2 features)
  _Float16* xl2 = (_Float16*)(ws + 4 * szQ);
  _Float16* xr2 = (_Float16*)(ws + 5 * szQ);
  char* p = ws + 6 * szQ;
  int* deg = (int*)p;                                  p += (size_t)N * 4;
  int* row_ofs = (int*)p;                              p += (size_t)(N + 1) * 4;
  int* bsums = (int*)p;                                p += 128 * 4;
  int* hist = (int*)p;                                 p += 64 * 4;
  int* cursor2 = (int*)p;                              p += 64 * 4;
  int* order = (int*)p;                                p += (size_t)N * 4;
  p = (char*)(((uintptr_t)p + 15) & ~(uintptr_t)15);
  int* rank = (int*)p;                                 p += (size_t)ET * 4;
  p = (char*)(((uintptr_t)p + 15) & ~(uintptr_t)15);
  int* csr_src = (int*)p;                              p += (size_t)ET * 4;
  p = (char*)(((uintptr_t)p + 15) & ~(uintptr_t)15);
  _Float16* wt1 = (_Float16*)p;                        p += 8192 * 2;
  _Float16* wt2 = (_Float16*)p;                        p += 8192 * 2;
  _Float16* wt3 = (_Float16*)p;                        p += 16384 * 2;
  p = (char*)(((uintptr_t)p + 15) & ~(uintptr_t)15);
  int* cnt2 = (int*)p;                                 p += (size_t)N * NS * 4;

  const int edgeBlocks = (ET + 255) / 256;
  const int nodeBlocks = (N + 255) / 256;
  const int nh2Blocks = (N * HEADS * 2 + 255) / 256;
  const int rowBlocks = (N + 63) / 64;
  const int scanBlocks = (N + 1023) / 1024;  // 98 <= 128
  const int nSlice = (N + 7) / 8;

  // ---- preamble + layer-1 GEMM (fused/overlapped), R19b structure ----
  wt_build_zero_kernel<<<512, 256, 0, stream>>>(W1l, W1r, W2l, W2r, W3l, W3r,
                                                wt1, wt2, wt3, cnt2, hist,
                                                cursor2, N * NS);
  gemm1_count_kernel<<<rowBlocks + edgeBlocks, 256, 0, stream>>>(
      x, wt1, xl1, xr1, ei, E, ET, N, cnt2, rank, rowBlocks);
  slicescan_kernel<<<scanBlocks, 256, 0, stream>>>(cnt2, deg, row_ofs, bsums,
                                                   hist, N, NS);
  finalize2_kernel<<<nodeBlocks, 256, 0, stream>>>(
      row_ofs, bsums, deg, hist, cursor2, order, N, ET, scanBlocks);
  fill_kernel<<<8 * 96, 256, 0, stream>>>(ei, rank, row_ofs, cnt2, E, ET, N,
                                          nSlice, csr_src);

  // ---- Layer 1 agg + fused layer-2 GEMM ----
  node_agg_kernel<16, 0, 128><<<nh2Blocks, 256, 0, stream>>>(
      xl1, xr1, a1, b1, row_ofs, csr_src, order, wt2, xl2, xr2, nullptr, N);
  // ---- Layer 2 agg + fused layer-3 GEMM ----
  node_agg_kernel<16, 0, 256><<<nh2Blocks, 256, 0, stream>>>(
      xl2, xr2, a2, b2, row_ofs, csr_src, order, wt3, xl3, xr3, nullptr, N);
  // ---- Layer 3 agg: mean over heads -> output ----
  node_agg_kernel<32, 1, 16><<<nh2Blocks, 256, 0, stream>>>(
      xl3, xr3, a3, b3, row_ofs, csr_src, order, nullptr, nullptr, nullptr,
      d_out, N);
}